// Round 1
// baseline (149.946 us; speedup 1.0000x reference)
//
#include <hip/hip_runtime.h>
#include <hip/hip_bf16.h>
#include <stdint.h>
#include <stddef.h>

typedef __bf16 bf16_t;
typedef __attribute__((ext_vector_type(8))) __bf16 bf16x8;
typedef __attribute__((ext_vector_type(4))) float f32x4;

#define TOK 2048      // N*M tokens
#define DMODEL 1024
#define NHEAD 16
#define DKH 64

// ---------------- fp32 -> bf16 batched convert ----------------
struct CvtArgs {
  const float* src[7];
  bf16_t* dst[7];
  int n[7];
};

__global__ __launch_bounds__(256) void cvt_kernel(CvtArgs a) {
  int arr = blockIdx.y;
  int n = a.n[arr];
  int i = (blockIdx.x * 256 + threadIdx.x) * 8;
  if (i >= n) return;            // n is always a multiple of 8
  const float* s = a.src[arr];
  bf16_t* d = a.dst[arr];
  f32x4 x0 = *(const f32x4*)(s + i);
  f32x4 x1 = *(const f32x4*)(s + i + 4);
  bf16x8 o;
  o[0] = (bf16_t)x0[0]; o[1] = (bf16_t)x0[1]; o[2] = (bf16_t)x0[2]; o[3] = (bf16_t)x0[3];
  o[4] = (bf16_t)x1[0]; o[5] = (bf16_t)x1[1]; o[6] = (bf16_t)x1[2]; o[7] = (bf16_t)x1[3];
  *(bf16x8*)(d + i) = o;
}

// ---------------- bf16 MFMA GEMM: C[t][j] = sum_k A[t][k]*W[j][k] + bias[j] ----------------
// 128x128 tile, BK=64, 4 waves (2x2 of 64x64), 16x16x32 MFMA, padded LDS (reg-staged).
#define BM 128
#define BN 128
#define BK 64
#define LDK 72   // +8 bf16 pad: row stride 144B -> 2-way bank alias only (free)

struct GemmArgs {
  const bf16_t* A[3];
  const bf16_t* W[3];
  const float* bias[3];
  void* C[3];
};

template <typename CT>
__global__ __launch_bounds__(256, 2) void gemm_bt(GemmArgs g, int M, int N, int K) {
  const int z = blockIdx.z;
  const bf16_t* __restrict__ A = g.A[z];
  const bf16_t* __restrict__ W = g.W[z];
  const float* __restrict__ bias = g.bias[z];
  CT* __restrict__ C = (CT*)g.C[z];

  __shared__ alignas(16) bf16_t As[BM][LDK];
  __shared__ alignas(16) bf16_t Bs[BN][LDK];

  const int tid = threadIdx.x;
  const int wv = tid >> 6, lane = tid & 63;
  const int bm = blockIdx.x * BM, bn = blockIdx.y * BN;
  const int wr = (wv >> 1) * 64, wc = (wv & 1) * 64;   // wave's 64x64 quadrant
  const int lm = lane & 15;          // fragment row/col within 16
  const int lk = (lane >> 4) * 8;    // k-offset within 32

  f32x4 acc[4][4] = {};

  const int srow = tid >> 3;             // staging: 8 threads per row
  const int scol = (tid & 7) * 8;        // each thread one 8-elem (16B) chunk

  for (int k0 = 0; k0 < K; k0 += BK) {
#pragma unroll
    for (int i = 0; i < 4; ++i) {
      int r = srow + i * 32;
      *(bf16x8*)&As[r][scol] = *(const bf16x8*)&A[(size_t)(bm + r) * K + (k0 + scol)];
      *(bf16x8*)&Bs[r][scol] = *(const bf16x8*)&W[(size_t)(bn + r) * K + (k0 + scol)];
    }
    __syncthreads();
#pragma unroll
    for (int kk = 0; kk < BK; kk += 32) {
      bf16x8 af[4], bf[4];
#pragma unroll
      for (int i = 0; i < 4; ++i) af[i] = *(const bf16x8*)&As[wr + i * 16 + lm][kk + lk];
#pragma unroll
      for (int j = 0; j < 4; ++j) bf[j] = *(const bf16x8*)&Bs[wc + j * 16 + lm][kk + lk];
#pragma unroll
      for (int i = 0; i < 4; ++i)
#pragma unroll
        for (int j = 0; j < 4; ++j)
          acc[i][j] = __builtin_amdgcn_mfma_f32_16x16x32_bf16(af[i], bf[j], acc[i][j], 0, 0, 0);
    }
    __syncthreads();
  }

  // epilogue: D layout col = lane&15, row = (lane>>4)*4 + reg
  const int cr4 = (lane >> 4) * 4;
#pragma unroll
  for (int i = 0; i < 4; ++i) {
#pragma unroll
    for (int j = 0; j < 4; ++j) {
      int col = bn + wc + j * 16 + lm;
      float bv = bias[col];
#pragma unroll
      for (int r = 0; r < 4; ++r) {
        int row = bm + wr + i * 16 + cr4 + r;
        C[(size_t)row * N + col] = (CT)(acc[i][j][r] + bv);
      }
    }
  }
}

// ---------------- per-(token,head) channel attention ----------------
// ctx[d] = sum_q softmax_q( q_d * k_q / 8 ) * v_q   for d,q in 0..63
// one wave per (token,head) pair; lane owns d.
__global__ __launch_bounds__(256) void attn_kernel(
    const bf16_t* __restrict__ q, const bf16_t* __restrict__ k,
    const bf16_t* __restrict__ v, bf16_t* __restrict__ ctx) {
  __shared__ float kv[4][64][2];
  const int wv = threadIdx.x >> 6, lane = threadIdx.x & 63;
  const int pair = blockIdx.x * 4 + wv;          // t*16 + h
  const size_t base = (size_t)pair * 64;
  float qd = (float)q[base + lane];
  float kd = (float)k[base + lane];
  float vd = (float)v[base + lane];
  kv[wv][lane][0] = kd;
  kv[wv][lane][1] = vd;
  __syncthreads();

  // exact row max: max_q (a*k_q) = max(a*kmax, a*kmin)
  float kmax = kd, kmin = kd;
#pragma unroll
  for (int off = 32; off; off >>= 1) {
    kmax = fmaxf(kmax, __shfl_xor(kmax, off));
    kmin = fminf(kmin, __shfl_xor(kmin, off));
  }
  const float sc = 0.125f * 1.44269504088896341f;  // (1/sqrt(64)) * log2(e)
  float a = (float)qd * sc;
  float m = fmaxf(a * kmax, a * kmin);
  float sum = 0.f, accv = 0.f;
#pragma unroll 8
  for (int j = 0; j < 64; ++j) {
    float kj = kv[wv][j][0];
    float vj = kv[wv][j][1];
    float e = exp2f(fmaf(a, kj, -m));
    sum += e;
    accv = fmaf(e, vj, accv);
  }
  ctx[base + lane] = (bf16_t)(accv / sum);
}

// ---------------- launch ----------------
extern "C" void kernel_launch(void* const* d_in, const int* in_sizes, int n_in,
                              void* d_out, int out_size, void* d_ws, size_t ws_size,
                              hipStream_t stream) {
  const float* query = (const float*)d_in[0];
  const float* key   = (const float*)d_in[1];
  const float* value = (const float*)d_in[2];
  const float* Wq = (const float*)d_in[3];
  const float* bq = (const float*)d_in[4];
  const float* Wk = (const float*)d_in[5];
  const float* bk = (const float*)d_in[6];
  const float* Wv = (const float*)d_in[7];
  const float* bv = (const float*)d_in[8];
  const float* Wo = (const float*)d_in[9];
  const float* bo = (const float*)d_in[10];
  float* out = (float*)d_out;

  const size_t XE = (size_t)TOK * DMODEL;     // 2,097,152 elems
  const size_t WE = (size_t)DMODEL * DMODEL;  // 1,048,576 elems

  char* ws = (char*)d_ws;
  size_t off = 0;
  bf16_t* xb[3];
  for (int i = 0; i < 3; ++i) { xb[i] = (bf16_t*)(ws + off); off += XE * 2; }
  bf16_t* wb[4];
  for (int i = 0; i < 4; ++i) { wb[i] = (bf16_t*)(ws + off); off += WE * 2; }
  bf16_t* pb[3];   // projected q,k,v (bf16)
  for (int i = 0; i < 3; ++i) { pb[i] = (bf16_t*)(ws + off); off += XE * 2; }
  bf16_t* ctxb = (bf16_t*)(ws + off); off += XE * 2;
  // total ws use: 36 MB

  // 1) convert inputs + weights to bf16
  CvtArgs ca;
  ca.src[0] = query; ca.src[1] = key; ca.src[2] = value;
  ca.src[3] = Wq; ca.src[4] = Wk; ca.src[5] = Wv; ca.src[6] = Wo;
  ca.dst[0] = xb[0]; ca.dst[1] = xb[1]; ca.dst[2] = xb[2];
  ca.dst[3] = wb[0]; ca.dst[4] = wb[1]; ca.dst[5] = wb[2]; ca.dst[6] = wb[3];
  ca.n[0] = ca.n[1] = ca.n[2] = (int)XE;
  ca.n[3] = ca.n[4] = ca.n[5] = ca.n[6] = (int)WE;
  cvt_kernel<<<dim3((unsigned)(XE / (256 * 8)), 7), 256, 0, stream>>>(ca);

  // 2) fused QKV projection (batched over z)
  GemmArgs g1;
  g1.A[0] = xb[0]; g1.A[1] = xb[1]; g1.A[2] = xb[2];
  g1.W[0] = wb[0]; g1.W[1] = wb[1]; g1.W[2] = wb[2];
  g1.bias[0] = bq; g1.bias[1] = bk; g1.bias[2] = bv;
  g1.C[0] = pb[0]; g1.C[1] = pb[1]; g1.C[2] = pb[2];
  gemm_bt<bf16_t><<<dim3(TOK / BM, DMODEL / BN, 3), 256, 0, stream>>>(g1, TOK, DMODEL, DMODEL);

  // 3) per-(token,head) channel attention
  attn_kernel<<<dim3(TOK * NHEAD / 4), 256, 0, stream>>>(pb[0], pb[1], pb[2], ctxb);

  // 4) output projection -> fp32 out
  GemmArgs g2;
  g2.A[0] = ctxb; g2.A[1] = ctxb; g2.A[2] = ctxb;
  g2.W[0] = wb[3]; g2.W[1] = wb[3]; g2.W[2] = wb[3];
  g2.bias[0] = bo; g2.bias[1] = bo; g2.bias[2] = bo;
  g2.C[0] = out; g2.C[1] = out; g2.C[2] = out;
  gemm_bt<float><<<dim3(TOK / BM, DMODEL / BN, 1), 256, 0, stream>>>(g2, TOK, DMODEL, DMODEL);
}

// Round 2
// 85.781 us; speedup vs baseline: 1.7480x; 1.7480x over previous
//
#include <hip/hip_runtime.h>
#include <hip/hip_bf16.h>
#include <stdint.h>
#include <stddef.h>

typedef __bf16 bf16_t;
typedef __attribute__((ext_vector_type(8))) __bf16 bf16x8;
typedef __attribute__((ext_vector_type(4))) float f32x4;

#define TOK 2048      // N*M tokens
#define DMODEL 1024
#define NHEAD 16
#define DKH 64

// ---------------- fp32 -> bf16 batched convert ----------------
struct CvtArgs {
  const float* src[7];
  bf16_t* dst[7];
  int n[7];
};

__global__ __launch_bounds__(256) void cvt_kernel(CvtArgs a) {
  int arr = blockIdx.y;
  int n = a.n[arr];
  int i = (blockIdx.x * 256 + threadIdx.x) * 8;
  if (i >= n) return;            // n is always a multiple of 8
  const float* s = a.src[arr];
  bf16_t* d = a.dst[arr];
  f32x4 x0 = *(const f32x4*)(s + i);
  f32x4 x1 = *(const f32x4*)(s + i + 4);
  bf16x8 o;
  o[0] = (bf16_t)x0[0]; o[1] = (bf16_t)x0[1]; o[2] = (bf16_t)x0[2]; o[3] = (bf16_t)x0[3];
  o[4] = (bf16_t)x1[0]; o[5] = (bf16_t)x1[1]; o[6] = (bf16_t)x1[2]; o[7] = (bf16_t)x1[3];
  *(bf16x8*)(d + i) = o;
}

// ---------------- bf16 MFMA GEMM: C[t][j] = sum_k A[t][k]*W[j][k] + bias[j] ----------------
// 64x64 tile, BK=64, 4 waves (2x2 of 32x32), pipelined reg-staged prefetch,
// single LDS buffer (frags consumed into regs before overwrite barrier).
#define BM 64
#define BN 64
#define BK 64
#define LDK 72   // +8 bf16 pad: row stride 144B (16B-aligned, 9 quads) -> ~2-way alias

struct GemmArgs {
  const bf16_t* A[3];
  const bf16_t* W[3];
  const float* bias[3];
  void* C[3];
};

template <typename CT>
__global__ __launch_bounds__(256) void gemm_bt(GemmArgs g, int M, int N, int K) {
  const int z = blockIdx.z;
  const bf16_t* __restrict__ A = g.A[z];
  const bf16_t* __restrict__ W = g.W[z];
  const float* __restrict__ bias = g.bias[z];
  CT* __restrict__ C = (CT*)g.C[z];

  // bijective XCD swizzle (nwg per z is a multiple of 8)
  const int nwg = gridDim.x * gridDim.y;
  const int oldid = blockIdx.x + gridDim.x * blockIdx.y;
  const int cpx = nwg >> 3;
  const int nid = (oldid & 7) * cpx + (oldid >> 3);
  const int bm = (nid % gridDim.x) * BM;
  const int bn = (nid / gridDim.x) * BN;

  __shared__ alignas(16) bf16_t As[BM][LDK];
  __shared__ alignas(16) bf16_t Bs[BN][LDK];

  const int tid = threadIdx.x;
  const int wv = tid >> 6, lane = tid & 63;
  const int wr = (wv >> 1) * 32, wc = (wv & 1) * 32;   // wave's 32x32 quadrant
  const int lm = lane & 15;
  const int lk = (lane >> 4) * 8;

  // staging: thread t -> row tid>>2, two 8-elem chunks at col (tid&3)*16
  const int trow = tid >> 2;
  const int tcol = (tid & 3) * 16;

  const bf16_t* arow = A + (size_t)(bm + trow) * K + tcol;
  const bf16_t* wrow = W + (size_t)(bn + trow) * K + tcol;

  f32x4 acc[2][2] = {};

  // prologue: stage tile 0
  {
    bf16x8 a0 = *(const bf16x8*)(arow);
    bf16x8 a1 = *(const bf16x8*)(arow + 8);
    bf16x8 w0 = *(const bf16x8*)(wrow);
    bf16x8 w1 = *(const bf16x8*)(wrow + 8);
    *(bf16x8*)&As[trow][tcol] = a0;
    *(bf16x8*)&As[trow][tcol + 8] = a1;
    *(bf16x8*)&Bs[trow][tcol] = w0;
    *(bf16x8*)&Bs[trow][tcol + 8] = w1;
  }
  __syncthreads();

  const int nt = K / BK;
  for (int t = 0; t < nt; ++t) {
    // issue prefetch of tile t+1 into regs (latency hides under this iter)
    bf16x8 na0, na1, nw0, nw1;
    const bool more = (t + 1) < nt;
    if (more) {
      const bf16_t* ap = arow + (size_t)(t + 1) * BK;
      const bf16_t* wp = wrow + (size_t)(t + 1) * BK;
      na0 = *(const bf16x8*)(ap);
      na1 = *(const bf16x8*)(ap + 8);
      nw0 = *(const bf16x8*)(wp);
      nw1 = *(const bf16x8*)(wp + 8);
    }

    // ds_read all fragments for this tile into regs
    bf16x8 fa[2][2], fb[2][2];   // [kk][i]
#pragma unroll
    for (int kk = 0; kk < 2; ++kk) {
#pragma unroll
      for (int i = 0; i < 2; ++i) {
        fa[kk][i] = *(const bf16x8*)&As[wr + i * 16 + lm][kk * 32 + lk];
        fb[kk][i] = *(const bf16x8*)&Bs[wc + i * 16 + lm][kk * 32 + lk];
      }
    }
    // all waves finished reading LDS -> safe to overwrite. lgkm-only wait
    // (NOT __syncthreads: that drains vmcnt(0) and kills the prefetch).
    asm volatile("s_waitcnt lgkmcnt(0)" ::: "memory");
    __builtin_amdgcn_sched_barrier(0);
    __builtin_amdgcn_s_barrier();

#pragma unroll
    for (int kk = 0; kk < 2; ++kk)
#pragma unroll
      for (int i = 0; i < 2; ++i)
#pragma unroll
        for (int j = 0; j < 2; ++j)
          acc[i][j] = __builtin_amdgcn_mfma_f32_16x16x32_bf16(fa[kk][i], fb[kk][j], acc[i][j], 0, 0, 0);

    if (more) {
      // compiler inserts vmcnt waits for the prefetch regs here; MFMAs above
      // are independent and overlap the wait.
      *(bf16x8*)&As[trow][tcol] = na0;
      *(bf16x8*)&As[trow][tcol + 8] = na1;
      *(bf16x8*)&Bs[trow][tcol] = nw0;
      *(bf16x8*)&Bs[trow][tcol + 8] = nw1;
      asm volatile("s_waitcnt lgkmcnt(0)" ::: "memory");
      __builtin_amdgcn_sched_barrier(0);
      __builtin_amdgcn_s_barrier();
    }
  }

  // epilogue: D layout col = lane&15, row = (lane>>4)*4 + reg
  const int cr4 = (lane >> 4) * 4;
#pragma unroll
  for (int i = 0; i < 2; ++i) {
#pragma unroll
    for (int j = 0; j < 2; ++j) {
      int col = bn + wc + j * 16 + lm;
      float bv = bias[col];
#pragma unroll
      for (int r = 0; r < 4; ++r) {
        int row = bm + wr + i * 16 + cr4 + r;
        C[(size_t)row * N + col] = (CT)(acc[i][j][r] + bv);
      }
    }
  }
}

// ---------------- per-(token,head) channel attention ----------------
// ctx[d] = sum_q softmax_q( q_d * k_q / 8 ) * v_q   for d,q in 0..63
// one wave per (token,head) pair; lane owns d.
__global__ __launch_bounds__(256) void attn_kernel(
    const bf16_t* __restrict__ q, const bf16_t* __restrict__ k,
    const bf16_t* __restrict__ v, bf16_t* __restrict__ ctx) {
  __shared__ float kv[4][64][2];
  const int wv = threadIdx.x >> 6, lane = threadIdx.x & 63;
  const int pair = blockIdx.x * 4 + wv;          // t*16 + h
  const size_t base = (size_t)pair * 64;
  float qd = (float)q[base + lane];
  float kd = (float)k[base + lane];
  float vd = (float)v[base + lane];
  kv[wv][lane][0] = kd;
  kv[wv][lane][1] = vd;
  __syncthreads();

  // exact row max: max_q (a*k_q) = max(a*kmax, a*kmin)
  float kmax = kd, kmin = kd;
#pragma unroll
  for (int off = 32; off; off >>= 1) {
    kmax = fmaxf(kmax, __shfl_xor(kmax, off));
    kmin = fminf(kmin, __shfl_xor(kmin, off));
  }
  const float sc = 0.125f * 1.44269504088896341f;  // (1/sqrt(64)) * log2(e)
  float a = (float)qd * sc;
  float m = fmaxf(a * kmax, a * kmin);
  float sum = 0.f, accv = 0.f;
#pragma unroll 8
  for (int j = 0; j < 64; ++j) {
    float kj = kv[wv][j][0];
    float vj = kv[wv][j][1];
    float e = exp2f(fmaf(a, kj, -m));
    sum += e;
    accv = fmaf(e, vj, accv);
  }
  ctx[base + lane] = (bf16_t)(accv * __builtin_amdgcn_rcpf(sum));
}

// ---------------- launch ----------------
extern "C" void kernel_launch(void* const* d_in, const int* in_sizes, int n_in,
                              void* d_out, int out_size, void* d_ws, size_t ws_size,
                              hipStream_t stream) {
  const float* query = (const float*)d_in[0];
  const float* key   = (const float*)d_in[1];
  const float* value = (const float*)d_in[2];
  const float* Wq = (const float*)d_in[3];
  const float* bq = (const float*)d_in[4];
  const float* Wk = (const float*)d_in[5];
  const float* bk = (const float*)d_in[6];
  const float* Wv = (const float*)d_in[7];
  const float* bv = (const float*)d_in[8];
  const float* Wo = (const float*)d_in[9];
  const float* bo = (const float*)d_in[10];
  float* out = (float*)d_out;

  const size_t XE = (size_t)TOK * DMODEL;     // 2,097,152 elems
  const size_t WE = (size_t)DMODEL * DMODEL;  // 1,048,576 elems

  char* ws = (char*)d_ws;
  size_t off = 0;
  bf16_t* xb[3];
  for (int i = 0; i < 3; ++i) { xb[i] = (bf16_t*)(ws + off); off += XE * 2; }
  bf16_t* wb[4];
  for (int i = 0; i < 4; ++i) { wb[i] = (bf16_t*)(ws + off); off += WE * 2; }
  bf16_t* pb[3];   // projected q,k,v (bf16)
  for (int i = 0; i < 3; ++i) { pb[i] = (bf16_t*)(ws + off); off += XE * 2; }
  bf16_t* ctxb = (bf16_t*)(ws + off); off += XE * 2;

  // 1) convert inputs + weights to bf16
  CvtArgs ca;
  ca.src[0] = query; ca.src[1] = key; ca.src[2] = value;
  ca.src[3] = Wq; ca.src[4] = Wk; ca.src[5] = Wv; ca.src[6] = Wo;
  ca.dst[0] = xb[0]; ca.dst[1] = xb[1]; ca.dst[2] = xb[2];
  ca.dst[3] = wb[0]; ca.dst[4] = wb[1]; ca.dst[5] = wb[2]; ca.dst[6] = wb[3];
  ca.n[0] = ca.n[1] = ca.n[2] = (int)XE;
  ca.n[3] = ca.n[4] = ca.n[5] = ca.n[6] = (int)WE;
  cvt_kernel<<<dim3((unsigned)(XE / (256 * 8)), 7), 256, 0, stream>>>(ca);

  // 2) fused QKV projection (batched over z): grid 32x16x3 = 1536 blocks
  GemmArgs g1;
  g1.A[0] = xb[0]; g1.A[1] = xb[1]; g1.A[2] = xb[2];
  g1.W[0] = wb[0]; g1.W[1] = wb[1]; g1.W[2] = wb[2];
  g1.bias[0] = bq; g1.bias[1] = bk; g1.bias[2] = bv;
  g1.C[0] = pb[0]; g1.C[1] = pb[1]; g1.C[2] = pb[2];
  gemm_bt<bf16_t><<<dim3(TOK / BM, DMODEL / BN, 3), 256, 0, stream>>>(g1, TOK, DMODEL, DMODEL);

  // 3) per-(token,head) channel attention
  attn_kernel<<<dim3(TOK * NHEAD / 4), 256, 0, stream>>>(pb[0], pb[1], pb[2], ctxb);

  // 4) output projection -> fp32 out: grid 32x16 = 512 blocks
  GemmArgs g2;
  g2.A[0] = ctxb; g2.A[1] = ctxb; g2.A[2] = ctxb;
  g2.W[0] = wb[3]; g2.W[1] = wb[3]; g2.W[2] = wb[3];
  g2.bias[0] = bo; g2.bias[1] = bo; g2.bias[2] = bo;
  g2.C[0] = out; g2.C[1] = out; g2.C[2] = out;
  gemm_bt<float><<<dim3(TOK / BM, DMODEL / BN, 1), 256, 0, stream>>>(g2, TOK, DMODEL, DMODEL);
}